// Round 7
// baseline (395.085 us; speedup 1.0000x reference)
//
#include <hip/hip_runtime.h>
#include <stdint.h>

#define B_ROWS 2048
#define D2_DIM 256
#define D_DIM 128
#define M_ITEMS 100000
#define M_PAD 100352           // 196 * 512
#define BN_EPS_F 1e-5f
#define COS_EPS_F 1e-6f
#define LEAKY_F 0.01f

#define BNI 128                // items per tile
#define BKS 64                 // K per stage
#define SUPER 4                // item tiles per block -> 512 items/block
#define NSTEPS 8               // SUPER * (D_DIM/BKS)

typedef __bf16 bf16x8 __attribute__((ext_vector_type(8)));
typedef float f32x4 __attribute__((ext_vector_type(4)));

// bf16 hi/lo split planes (device globals; rebuilt every call)
__device__ unsigned short g_Aph[B_ROWS * D_DIM];
__device__ unsigned short g_Apl[B_ROWS * D_DIM];
__device__ unsigned short g_Bph[M_PAD * D_DIM];
__device__ unsigned short g_Bpl[M_PAD * D_DIM];

__device__ __forceinline__ unsigned bf16_rne(float f) {
  unsigned u = __float_as_uint(f);
  return (u + 0x7fffu + ((u >> 16) & 1u)) >> 16;
}
__device__ __forceinline__ void split_bf16(float v, unsigned short& hi, unsigned short& lo) {
  unsigned h = bf16_rne(v);
  float hf = __uint_as_float(h << 16);
  unsigned l = bf16_rne(v - hf);   // exact residual
  hi = (unsigned short)h; lo = (unsigned short)l;
}
__device__ __forceinline__ void gload16(const void* g, void* l) {
  __builtin_amdgcn_global_load_lds(
      (const __attribute__((address_space(1))) void*)g,
      (__attribute__((address_space(3))) void*)l, 16, 0, 0);
}

// ---------- kernel 1: h = item_feature @ W + b ----------
__global__ void k_gemm1(const float* __restrict__ A, const float* __restrict__ W,
                        const float* __restrict__ bias, float* __restrict__ h) {
  __shared__ float arow[D2_DIM];
  const int r = blockIdx.x;
  const int c = threadIdx.x;  // 128
  arow[c] = A[r * D2_DIM + c];
  arow[c + 128] = A[r * D2_DIM + c + 128];
  __syncthreads();
  float acc = 0.f;
#pragma unroll 8
  for (int k = 0; k < D2_DIM; k++) acc = fmaf(arow[k], W[k * D_DIM + c], acc);
  h[r * D_DIM + c] = acc + bias[c];
}

// ---------- kernel 2: per-column mean/var -> scale/shift ----------
__global__ void k_bnstats(const float* __restrict__ h, const float* __restrict__ gamma,
                          const float* __restrict__ beta, float* __restrict__ scale,
                          float* __restrict__ shift) {
  const int c = blockIdx.x;
  const int t = threadIdx.x;  // 256
  double s = 0.0, sq = 0.0;
  for (int r = t; r < B_ROWS; r += 256) {
    double v = (double)h[r * D_DIM + c];
    s += v; sq += v * v;
  }
  __shared__ double ls[256], lq[256];
  ls[t] = s; lq[t] = sq;
  __syncthreads();
  for (int off = 128; off; off >>= 1) {
    if (t < off) { ls[t] += ls[t + off]; lq[t] += lq[t + off]; }
    __syncthreads();
  }
  if (t == 0) {
    double mean = ls[0] / (double)B_ROWS;
    double var = lq[0] / (double)B_ROWS - mean * mean;
    float sc = (float)((double)gamma[c] / sqrt(var + (double)BN_EPS_F));
    scale[c] = sc;
    shift[c] = beta[c] - (float)mean * sc;
  }
}

// ---------- kernel 3: uf = leaky(bn(h)) -> bf16 hi/lo planes ----------
__global__ void k_norm_split(const float* __restrict__ h, const float* __restrict__ scale,
                             const float* __restrict__ shift) {
  int i = blockIdx.x * 256 + threadIdx.x;
  if (i >= B_ROWS * D_DIM) return;
  int c = i & (D_DIM - 1);
  float v = fmaf(h[i], scale[c], shift[c]);
  v = v >= 0.f ? v : LEAKY_F * v;
  unsigned short hi, lo;
  split_bf16(v, hi, lo);
  g_Aph[i] = hi; g_Apl[i] = lo;
}

// ---------- kernel 4: all_items -> bf16 hi/lo planes (pad rows zeroed) ----------
__global__ void k_build_items(const float* __restrict__ items) {
  long long t = (long long)blockIdx.x * 256 + threadIdx.x;
  long long base = t * 4;
  if (base >= (long long)M_PAD * D_DIM) return;
  float4 v;
  if (base < (long long)M_ITEMS * D_DIM) v = *(const float4*)&items[base];
  else v = make_float4(0.f, 0.f, 0.f, 0.f);
  ushort4 hv, lv;
  split_bf16(v.x, hv.x, lv.x);
  split_bf16(v.y, hv.y, lv.y);
  split_bf16(v.z, hv.z, lv.z);
  split_bf16(v.w, hv.w, lv.w);
  *(ushort4*)&g_Bph[base] = hv;
  *(ushort4*)&g_Bpl[base] = lv;
}

// ---------- kernel 5: init argmax keys ----------
__global__ void k_init(unsigned long long* __restrict__ keys) {
  int i = blockIdx.x * blockDim.x + threadIdx.x;
  if (i < B_ROWS) keys[i] = 0ull;
}

// ---------- kernel 6: MFMA scores + fused argmax ----------
// 256 threads / 4 waves (2x2), tile 128 rows x 128 items, SUPER=4 tiles.
// BK=64 steps (8 total): half the barriers of R6. B in 2-deep 32KB-stage ring
// (LDS 64KB -> 2 blocks/CU). A-hi persistent in regs; A-lo streamed per-step
// from L2 into transient regs (no LDS, no persistent cost).
// B swizzle (G21 both-sides): LDS slot sig holds global k-quad sig^(item&7);
// stage-write linear (gload_lds), read XORs back -> 2-way conflict (free).
__launch_bounds__(256, 2)
__global__ void k_scores_mfma(unsigned long long* __restrict__ keys) {
  __shared__ __align__(16) char smem[65536];
  char* bufs[2] = { smem, smem + 32768 };  // each: hi 16KB + lo 16KB

  const int tid = threadIdx.x;
  const int l = tid & 63;
  const int w = tid >> 6;      // 0..3
  const int wm = w >> 1;       // row half
  const int wn = w & 1;        // item half
  const int rowbase = blockIdx.x * 128;          // row-block FAST -> B locality
  const int chunk = blockIdx.y * (SUPER * BNI);  // item chunk slow
  const int lrow = l & 15;
  const int lkg = l >> 4;      // 0..3

  // ---- B stage (32KB): plane slot s (item=s>>3, sig=s&7) holds k-quad
  // sig^(item&7); LDS dest linear, source pre-swizzled.
  auto STAGEB = [&](int itembase, int ks, char* buf) {
#pragma unroll
    for (int rep = 0; rep < 4; rep++) {
      const int s = tid + rep * 256;      // 1024 slots per plane
      const size_t goff = (size_t)(itembase + (s >> 3)) * D_DIM + ks
                        + (((s & 7) ^ ((s >> 3) & 7)) * 8);
      gload16(g_Bph + goff, buf + s * 16);
      gload16(g_Bpl + goff, buf + 16384 + s * 16);
    }
  };

  // ---- prologue: stage 0 in flight, then A-hi -> regs ----
  STAGEB(chunk, 0, bufs[0]);
  bf16x8 ah[4][4];
  const int ar = rowbase + wm * 64 + lrow;
#pragma unroll
  for (int mi = 0; mi < 4; mi++)
#pragma unroll
    for (int kf = 0; kf < 4; kf++)
      ah[mi][kf] = *(const bf16x8*)&g_Aph[(size_t)(ar + mi * 16) * D_DIM + kf * 32 + lkg * 8];

  float bestv[16];
  int besti[16];
#pragma unroll
  for (int q = 0; q < 16; q++) { bestv[q] = -3.0e38f; besti[q] = 0x7fffffff; }

  f32x4 acc[4][4];
#pragma unroll
  for (int mi = 0; mi < 4; mi++)
#pragma unroll
    for (int ni = 0; ni < 4; ni++) acc[mi][ni] = (f32x4)(0.0f);

#pragma unroll
  for (int s = 0; s < SUPER; s++) {
    const int itembase = chunk + s * BNI;
#pragma unroll
    for (int khalf = 0; khalf < 2; khalf++) {
      const int j = s * 2 + khalf;
      // stage j (issued one full step ago) must be complete everywhere
      asm volatile("s_waitcnt vmcnt(0)" ::: "memory");
      __builtin_amdgcn_s_barrier();
      if (j < NSTEPS - 1) {
        const int q = j + 1;
        STAGEB(chunk + (q >> 1) * BNI, (q & 1) * BKS, bufs[q & 1]);
      }
      // A-lo for this step: 8 transient frags from L2
      bf16x8 alo0[4], alo1[4];
#pragma unroll
      for (int mi = 0; mi < 4; mi++) {
        const size_t abase = (size_t)(ar + mi * 16) * D_DIM + khalf * 64 + lkg * 8;
        alo0[mi] = *(const bf16x8*)&g_Apl[abase];
        alo1[mi] = *(const bf16x8*)&g_Apl[abase + 32];
      }
      char* buf = bufs[j & 1];
#pragma unroll
      for (int kk = 0; kk < 2; kk++) {
        const int kf = khalf * 2 + kk;
        bf16x8 bh[4], bl[4];
#pragma unroll
        for (int ni = 0; ni < 4; ni++) {
          const int item = wn * 64 + ni * 16 + lrow;
          const int q8 = kk * 4 + lkg;
          const int off = (item * 8 + (q8 ^ (item & 7))) * 16;
          bh[ni] = *(const bf16x8*)(buf + off);
          bl[ni] = *(const bf16x8*)(buf + 16384 + off);
        }
        __builtin_amdgcn_s_setprio(1);
#pragma unroll
        for (int mi = 0; mi < 4; mi++)
#pragma unroll
          for (int ni = 0; ni < 4; ni++) {
            f32x4 c = acc[mi][ni];
            c = __builtin_amdgcn_mfma_f32_16x16x32_bf16(ah[mi][kf], bh[ni], c, 0, 0, 0);
            c = __builtin_amdgcn_mfma_f32_16x16x32_bf16(kk ? alo1[mi] : alo0[mi], bh[ni], c, 0, 0, 0);
            c = __builtin_amdgcn_mfma_f32_16x16x32_bf16(ah[mi][kf], bl[ni], c, 0, 0, 0);
            acc[mi][ni] = c;
          }
        __builtin_amdgcn_s_setprio(0);
      }
    }
    // fold item tile into running best; reset acc
#pragma unroll
    for (int mi = 0; mi < 4; mi++)
#pragma unroll
      for (int ni = 0; ni < 4; ni++) {
        const int col = itembase + wn * 64 + ni * 16 + lrow;
        const bool valid = col < M_ITEMS;
#pragma unroll
        for (int reg = 0; reg < 4; reg++) {
          const float v = acc[mi][ni][reg];
          const int q = mi * 4 + reg;
          if (valid && v > bestv[q]) { bestv[q] = v; besti[q] = col; }
        }
        acc[mi][ni] = (f32x4)(0.0f);
      }
  }

  // reduce across 16 item-lanes, then one atomicMax per row
#pragma unroll
  for (int q = 0; q < 16; q++) {
    float v = bestv[q];
    int bi = besti[q];
#pragma unroll
    for (int off = 1; off < 16; off <<= 1) {
      float ov = __shfl_xor(v, off, 16);
      int oi = __shfl_xor(bi, off, 16);
      if (ov > v || (ov == v && oi < bi)) { v = ov; bi = oi; }
    }
    if (lrow == 0) {
      const int row = rowbase + wm * 64 + (q >> 2) * 16 + lkg * 4 + (q & 3);
      unsigned u = __float_as_uint(v);
      u = (u & 0x80000000u) ? ~u : (u | 0x80000000u);
      unsigned long long key =
          ((unsigned long long)u << 32) | (unsigned)(~(unsigned)bi);
      atomicMax(&keys[row], key);
    }
  }
}

// ---------- kernel 7: unpack top1, gather, cosine sim ----------
__global__ void k_post(const unsigned long long* __restrict__ keys,
                       const int* __restrict__ uid,
                       const float* __restrict__ items,
                       float* __restrict__ out, float* __restrict__ sims,
                       float* __restrict__ rl) {
  int r = blockIdx.x * blockDim.x + threadIdx.x;
  if (r >= B_ROWS) return;
  unsigned long long key = keys[r];
  int idx = (int)(~(unsigned)(key & 0xFFFFFFFFull));
  out[r] = (float)idx;
  int orig = uid[2 * r + 1];
  const float* a = items + (long long)orig * D_DIM;
  const float* c = items + (long long)idx * D_DIM;
  float aa = 0.f, cc = 0.f, ac = 0.f;
#pragma unroll 4
  for (int d = 0; d < D_DIM; d++) {
    float x = a[d], y = c[d];
    aa = fmaf(x, x, aa);
    cc = fmaf(y, y, cc);
    ac = fmaf(x, y, ac);
  }
  float na = fmaxf(sqrtf(aa), COS_EPS_F);
  float nc = fmaxf(sqrtf(cc), COS_EPS_F);
  float sim = ac / (na * nc);
  sim = (sim + 1.f) * 0.5f;
  sims[r] = sim;
  rl[r] = fmaxf(sim - 0.5f, 0.f);
}

// ---------- kernel 8: deterministic final means ----------
__global__ void k_final(const float* __restrict__ sims, const float* __restrict__ rl,
                        float* __restrict__ out) {
  __shared__ float s1[256], s2[256];
  int t = threadIdx.x;
  float a = 0.f, b = 0.f;
  for (int r = t; r < B_ROWS; r += 256) { a += rl[r]; b += sims[r]; }
  s1[t] = a; s2[t] = b;
  __syncthreads();
  for (int off = 128; off; off >>= 1) {
    if (t < off) { s1[t] += s1[t + off]; s2[t] += s2[t + off]; }
    __syncthreads();
  }
  if (t == 0) {
    out[B_ROWS] = s1[0] / (float)B_ROWS;
    out[B_ROWS + 1] = s2[0] / (float)B_ROWS;
  }
}

extern "C" void kernel_launch(void* const* d_in, const int* in_sizes, int n_in,
                              void* d_out, int out_size, void* d_ws, size_t ws_size,
                              hipStream_t stream) {
  const float* item_feature = (const float*)d_in[0];
  const float* all_items    = (const float*)d_in[1];
  const int*   uid          = (const int*)d_in[2];
  const float* W            = (const float*)d_in[3];
  const float* bias         = (const float*)d_in[4];
  const float* gamma        = (const float*)d_in[5];
  const float* beta         = (const float*)d_in[6];
  float* out = (float*)d_out;

  float* h     = (float*)d_ws;             // 2048*128
  float* scale = h + B_ROWS * D_DIM;       // 128
  float* shift = scale + D_DIM;            // 128
  unsigned long long* keys = (unsigned long long*)(shift + D_DIM);  // 2048
  float* sims  = (float*)(keys + B_ROWS);  // 2048
  float* rl    = sims + B_ROWS;            // 2048

  k_gemm1<<<B_ROWS, D_DIM, 0, stream>>>(item_feature, W, bias, h);
  k_bnstats<<<D_DIM, 256, 0, stream>>>(h, gamma, beta, scale, shift);
  k_norm_split<<<(B_ROWS * D_DIM + 255) / 256, 256, 0, stream>>>(h, scale, shift);
  k_build_items<<<(M_PAD * D_DIM / 4 + 255) / 256, 256, 0, stream>>>(all_items);
  k_init<<<(B_ROWS + 255) / 256, 256, 0, stream>>>(keys);
  dim3 sg(B_ROWS / 128, M_PAD / (SUPER * BNI));   // x = row-block (fast), y = item chunk
  k_scores_mfma<<<sg, 256, 0, stream>>>(keys);
  k_post<<<(B_ROWS + 255) / 256, 256, 0, stream>>>(keys, uid, all_items, out, sims, rl);
  k_final<<<1, 256, 0, stream>>>(sims, rl, out);
}

// Round 8
// 354.195 us; speedup vs baseline: 1.1154x; 1.1154x over previous
//
#include <hip/hip_runtime.h>
#include <stdint.h>

#define B_ROWS 2048
#define D2_DIM 256
#define D_DIM 128
#define M_ITEMS 100000
#define M_PAD 100352           // 196 * 512
#define BN_EPS_F 1e-5f
#define COS_EPS_F 1e-6f
#define LEAKY_F 0.01f

#define BNI 128                // items per tile
#define BK 32                  // K per stage
#define SUPER 4                // item tiles per block -> 512 items/block

typedef __bf16 bf16x8 __attribute__((ext_vector_type(8)));
typedef float f32x4 __attribute__((ext_vector_type(4)));

// bf16 hi/lo split planes (device globals; rebuilt every call)
__device__ unsigned short g_Aph[B_ROWS * D_DIM];
__device__ unsigned short g_Apl[B_ROWS * D_DIM];
__device__ unsigned short g_Bph[M_PAD * D_DIM];
__device__ unsigned short g_Bpl[M_PAD * D_DIM];

__device__ __forceinline__ unsigned bf16_rne(float f) {
  unsigned u = __float_as_uint(f);
  return (u + 0x7fffu + ((u >> 16) & 1u)) >> 16;
}
__device__ __forceinline__ void split_bf16(float v, unsigned short& hi, unsigned short& lo) {
  unsigned h = bf16_rne(v);
  float hf = __uint_as_float(h << 16);
  unsigned l = bf16_rne(v - hf);   // exact residual
  hi = (unsigned short)h; lo = (unsigned short)l;
}
__device__ __forceinline__ void gload16(const void* g, void* l) {
  __builtin_amdgcn_global_load_lds(
      (const __attribute__((address_space(1))) void*)g,
      (__attribute__((address_space(3))) void*)l, 16, 0, 0);
}

// ---------- kernel 1: h = item_feature @ W + b ----------
__global__ void k_gemm1(const float* __restrict__ A, const float* __restrict__ W,
                        const float* __restrict__ bias, float* __restrict__ h) {
  __shared__ float arow[D2_DIM];
  const int r = blockIdx.x;
  const int c = threadIdx.x;  // 128
  arow[c] = A[r * D2_DIM + c];
  arow[c + 128] = A[r * D2_DIM + c + 128];
  __syncthreads();
  float acc = 0.f;
#pragma unroll 8
  for (int k = 0; k < D2_DIM; k++) acc = fmaf(arow[k], W[k * D_DIM + c], acc);
  h[r * D_DIM + c] = acc + bias[c];
}

// ---------- kernel 2: per-column mean/var -> scale/shift ----------
__global__ void k_bnstats(const float* __restrict__ h, const float* __restrict__ gamma,
                          const float* __restrict__ beta, float* __restrict__ scale,
                          float* __restrict__ shift) {
  const int c = blockIdx.x;
  const int t = threadIdx.x;  // 256
  double s = 0.0, sq = 0.0;
  for (int r = t; r < B_ROWS; r += 256) {
    double v = (double)h[r * D_DIM + c];
    s += v; sq += v * v;
  }
  __shared__ double ls[256], lq[256];
  ls[t] = s; lq[t] = sq;
  __syncthreads();
  for (int off = 128; off; off >>= 1) {
    if (t < off) { ls[t] += ls[t + off]; lq[t] += lq[t + off]; }
    __syncthreads();
  }
  if (t == 0) {
    double mean = ls[0] / (double)B_ROWS;
    double var = lq[0] / (double)B_ROWS - mean * mean;
    float sc = (float)((double)gamma[c] / sqrt(var + (double)BN_EPS_F));
    scale[c] = sc;
    shift[c] = beta[c] - (float)mean * sc;
  }
}

// ---------- kernel 3: uf = leaky(bn(h)) -> bf16 hi/lo planes ----------
__global__ void k_norm_split(const float* __restrict__ h, const float* __restrict__ scale,
                             const float* __restrict__ shift) {
  int i = blockIdx.x * 256 + threadIdx.x;
  if (i >= B_ROWS * D_DIM) return;
  int c = i & (D_DIM - 1);
  float v = fmaf(h[i], scale[c], shift[c]);
  v = v >= 0.f ? v : LEAKY_F * v;
  unsigned short hi, lo;
  split_bf16(v, hi, lo);
  g_Aph[i] = hi; g_Apl[i] = lo;
}

// ---------- kernel 4: all_items -> bf16 hi/lo planes (pad rows zeroed) ----------
__global__ void k_build_items(const float* __restrict__ items) {
  long long t = (long long)blockIdx.x * 256 + threadIdx.x;
  long long base = t * 4;
  if (base >= (long long)M_PAD * D_DIM) return;
  float4 v;
  if (base < (long long)M_ITEMS * D_DIM) v = *(const float4*)&items[base];
  else v = make_float4(0.f, 0.f, 0.f, 0.f);
  ushort4 hv, lv;
  split_bf16(v.x, hv.x, lv.x);
  split_bf16(v.y, hv.y, lv.y);
  split_bf16(v.z, hv.z, lv.z);
  split_bf16(v.w, hv.w, lv.w);
  *(ushort4*)&g_Bph[base] = hv;
  *(ushort4*)&g_Bpl[base] = lv;
}

// ---------- kernel 5: init argmax keys ----------
__global__ void k_init(unsigned long long* __restrict__ keys) {
  int i = blockIdx.x * blockDim.x + threadIdx.x;
  if (i < B_ROWS) keys[i] = 0ull;
}

// ---------- kernel 6: MFMA scores + fused argmax ----------
// 256 threads / 4 waves (2x2), tile 128 rows x 128 items, SUPER=4 tiles.
// A-hi AND A-lo persistent in regs (128 VGPR) -> NO A reads from LDS.
// B in 3-deep 16KB ring (48KB LDS total -> 2 blocks/CU). R6's proven
// counted-vmcnt(4) + s_barrier + 2-ahead prefetch discipline, unchanged.
// LESSON(R7): nothing but the ring's global_load_lds may enter the vmcnt
// queue between prefetch issue and consumption.
// B swizzle (G21, proven 0-conflict in R6): plane slot s (item=s>>2, sig=s&3)
// holds k-quad sig^((item>>1)&3); source pre-swizzled, read XORs back.
// ds_read addresses: single base VGPR + 16-bit imm (buf*16384+plane*8192+ni*1024).
__launch_bounds__(256, 2)
__global__ void k_scores_mfma(unsigned long long* __restrict__ keys) {
  __shared__ __align__(16) char smem[49152];   // 3 x (hi 8KB + lo 8KB)

  const int tid = threadIdx.x;
  const int l = tid & 63;
  const int w = tid >> 6;      // 0..3
  const int wm = w >> 1;       // row half
  const int wn = w & 1;        // item half
  const int rowbase = blockIdx.x * 128;          // row-block FAST -> B locality
  const int chunk = blockIdx.y * (SUPER * BNI);  // item chunk slow
  const int lrow = l & 15;
  const int lkg = l >> 4;      // 0..3

  // per-thread constant offsets (computed once)
  // staging: slot s = tid + rep*256; byte off in plane = (s>>2)*256 + swz*16
  int tb0, tb1, ldst;
  {
    const int s0 = tid;
    const int s1 = tid + 256;
    tb0 = (s0 >> 2) * 256 + (((s0 & 3) ^ ((s0 >> 3) & 3)) * 16);
    tb1 = (s1 >> 2) * 256 + (((s1 & 3) ^ ((s1 >> 3) & 3)) * 16);
    ldst = tid * 16;           // LDS dest (linear), +4096 for rep 1
  }
  const char* gBh = (const char*)g_Bph;
  const char* gBl = (const char*)g_Bpl;

  // ---- B stage (hi 8KB @ buf, lo 8KB @ buf+8192), source pre-swizzled ----
  auto STAGEB = [&](int itembase, int ks, char* buf) {
    const size_t ub = (size_t)itembase * 256 + (size_t)ks * 2;
    gload16(gBh + ub + tb0, buf + ldst);
    gload16(gBl + ub + tb0, buf + 8192 + ldst);
    gload16(gBh + ub + tb1, buf + ldst + 4096);
    gload16(gBl + ub + tb1, buf + 8192 + ldst + 4096);
  };

  // ---- prologue: stages 0,1 in flight, then A-hi/A-lo -> regs ----
  STAGEB(chunk, 0, smem);
  STAGEB(chunk, BK, smem + 16384);

  bf16x8 ah[4][4], al[4][4];
  const int ar = rowbase + wm * 64 + lrow;
#pragma unroll
  for (int mi = 0; mi < 4; mi++)
#pragma unroll
    for (int kf = 0; kf < 4; kf++) {
      const size_t off = (size_t)(ar + mi * 16) * D_DIM + kf * 32 + lkg * 8;
      ah[mi][kf] = *(const bf16x8*)&g_Aph[off];
      al[mi][kf] = *(const bf16x8*)&g_Apl[off];
    }

  // ds_read base: all 16 reads/step = base + imm(buf*16384 + plane*8192 + ni*1024)
  // off(ni,plane,buf) = buf*16384 + plane*8192 + wn*4096 + ni*1024
  //                   + lrow*64 + (lkg^((lrow>>1)&3))*16
  char* lbase = smem + wn * 4096 + lrow * 64 + ((lkg ^ ((lrow >> 1) & 3)) << 4);

  float bestv[16];
  int besti[16];
#pragma unroll
  for (int q = 0; q < 16; q++) { bestv[q] = -3.0e38f; besti[q] = 0x7fffffff; }

  f32x4 acc[4][4];
#pragma unroll
  for (int mi = 0; mi < 4; mi++)
#pragma unroll
    for (int ni = 0; ni < 4; ni++) acc[mi][ni] = (f32x4)(0.0f);

#pragma unroll
  for (int s = 0; s < SUPER; s++) {
    const int itembase = chunk + s * BNI;
#pragma unroll
    for (int kf = 0; kf < 4; kf++) {
      const int j = s * 4 + kf;
      // own stage-j landed (stage j+1 stays in flight)
      asm volatile("s_waitcnt vmcnt(4)" ::: "memory");
      __builtin_amdgcn_s_barrier();   // all waves' stage-j landed; buf[(j+2)%3] free
      {
        const int q = j + 2;          // prefetch 2 steps ahead (tail: dummy reload)
        const int qt = (q >> 2) & (SUPER - 1);
        STAGEB(chunk + qt * BNI, (q & 3) * BK, smem + (q % 3) * 16384);
      }
      const int jb = (j % 3) * 16384;   // compile-time (loop fully unrolled)
      bf16x8 bh[4], bl[4];
#pragma unroll
      for (int ni = 0; ni < 4; ni++) {
        bh[ni] = *(const bf16x8*)(lbase + jb + ni * 1024);
        bl[ni] = *(const bf16x8*)(lbase + jb + 8192 + ni * 1024);
      }
      __builtin_amdgcn_s_setprio(1);
#pragma unroll
      for (int mi = 0; mi < 4; mi++)
#pragma unroll
        for (int ni = 0; ni < 4; ni++) {
          f32x4 c = acc[mi][ni];
          c = __builtin_amdgcn_mfma_f32_16x16x32_bf16(ah[mi][kf], bh[ni], c, 0, 0, 0);
          c = __builtin_amdgcn_mfma_f32_16x16x32_bf16(al[mi][kf], bh[ni], c, 0, 0, 0);
          c = __builtin_amdgcn_mfma_f32_16x16x32_bf16(ah[mi][kf], bl[ni], c, 0, 0, 0);
          acc[mi][ni] = c;
        }
      __builtin_amdgcn_s_setprio(0);
    }
    // fold item tile into running best; reset acc
#pragma unroll
    for (int mi = 0; mi < 4; mi++)
#pragma unroll
      for (int ni = 0; ni < 4; ni++) {
        const int col = itembase + wn * 64 + ni * 16 + lrow;
        const bool valid = col < M_ITEMS;
#pragma unroll
        for (int reg = 0; reg < 4; reg++) {
          const float v = acc[mi][ni][reg];
          const int q = mi * 4 + reg;
          if (valid && v > bestv[q]) { bestv[q] = v; besti[q] = col; }
        }
        acc[mi][ni] = (f32x4)(0.0f);
      }
  }
  asm volatile("s_waitcnt vmcnt(0)" ::: "memory");  // drain dummy tail prefetches

  // reduce across 16 item-lanes, then one atomicMax per row
#pragma unroll
  for (int q = 0; q < 16; q++) {
    float v = bestv[q];
    int bi = besti[q];
#pragma unroll
    for (int off = 1; off < 16; off <<= 1) {
      float ov = __shfl_xor(v, off, 16);
      int oi = __shfl_xor(bi, off, 16);
      if (ov > v || (ov == v && oi < bi)) { v = ov; bi = oi; }
    }
    if (lrow == 0) {
      const int row = rowbase + wm * 64 + (q >> 2) * 16 + lkg * 4 + (q & 3);
      unsigned u = __float_as_uint(v);
      u = (u & 0x80000000u) ? ~u : (u | 0x80000000u);
      unsigned long long key =
          ((unsigned long long)u << 32) | (unsigned)(~(unsigned)bi);
      atomicMax(&keys[row], key);
    }
  }
}

// ---------- kernel 7: unpack top1, gather, cosine sim ----------
__global__ void k_post(const unsigned long long* __restrict__ keys,
                       const int* __restrict__ uid,
                       const float* __restrict__ items,
                       float* __restrict__ out, float* __restrict__ sims,
                       float* __restrict__ rl) {
  int r = blockIdx.x * blockDim.x + threadIdx.x;
  if (r >= B_ROWS) return;
  unsigned long long key = keys[r];
  int idx = (int)(~(unsigned)(key & 0xFFFFFFFFull));
  out[r] = (float)idx;
  int orig = uid[2 * r + 1];
  const float* a = items + (long long)orig * D_DIM;
  const float* c = items + (long long)idx * D_DIM;
  float aa = 0.f, cc = 0.f, ac = 0.f;
#pragma unroll 4
  for (int d = 0; d < D_DIM; d++) {
    float x = a[d], y = c[d];
    aa = fmaf(x, x, aa);
    cc = fmaf(y, y, cc);
    ac = fmaf(x, y, ac);
  }
  float na = fmaxf(sqrtf(aa), COS_EPS_F);
  float nc = fmaxf(sqrtf(cc), COS_EPS_F);
  float sim = ac / (na * nc);
  sim = (sim + 1.f) * 0.5f;
  sims[r] = sim;
  rl[r] = fmaxf(sim - 0.5f, 0.f);
}

// ---------- kernel 8: deterministic final means ----------
__global__ void k_final(const float* __restrict__ sims, const float* __restrict__ rl,
                        float* __restrict__ out) {
  __shared__ float s1[256], s2[256];
  int t = threadIdx.x;
  float a = 0.f, b = 0.f;
  for (int r = t; r < B_ROWS; r += 256) { a += rl[r]; b += sims[r]; }
  s1[t] = a; s2[t] = b;
  __syncthreads();
  for (int off = 128; off; off >>= 1) {
    if (t < off) { s1[t] += s1[t + off]; s2[t] += s2[t + off]; }
    __syncthreads();
  }
  if (t == 0) {
    out[B_ROWS] = s1[0] / (float)B_ROWS;
    out[B_ROWS + 1] = s2[0] / (float)B_ROWS;
  }
}

extern "C" void kernel_launch(void* const* d_in, const int* in_sizes, int n_in,
                              void* d_out, int out_size, void* d_ws, size_t ws_size,
                              hipStream_t stream) {
  const float* item_feature = (const float*)d_in[0];
  const float* all_items    = (const float*)d_in[1];
  const int*   uid          = (const int*)d_in[2];
  const float* W            = (const float*)d_in[3];
  const float* bias         = (const float*)d_in[4];
  const float* gamma        = (const float*)d_in[5];
  const float* beta         = (const float*)d_in[6];
  float* out = (float*)d_out;

  float* h     = (float*)d_ws;             // 2048*128
  float* scale = h + B_ROWS * D_DIM;       // 128
  float* shift = scale + D_DIM;            // 128
  unsigned long long* keys = (unsigned long long*)(shift + D_DIM);  // 2048
  float* sims  = (float*)(keys + B_ROWS);  // 2048
  float* rl    = sims + B_ROWS;            // 2048

  k_gemm1<<<B_ROWS, D_DIM, 0, stream>>>(item_feature, W, bias, h);
  k_bnstats<<<D_DIM, 256, 0, stream>>>(h, gamma, beta, scale, shift);
  k_norm_split<<<(B_ROWS * D_DIM + 255) / 256, 256, 0, stream>>>(h, scale, shift);
  k_build_items<<<(M_PAD * D_DIM / 4 + 255) / 256, 256, 0, stream>>>(all_items);
  k_init<<<(B_ROWS + 255) / 256, 256, 0, stream>>>(keys);
  dim3 sg(B_ROWS / 128, M_PAD / (SUPER * BNI));   // x = row-block (fast), y = item chunk
  k_scores_mfma<<<sg, 256, 0, stream>>>(keys);
  k_post<<<(B_ROWS + 255) / 256, 256, 0, stream>>>(keys, uid, all_items, out, sims, rl);
  k_final<<<1, 256, 0, stream>>>(sims, rl, out);
}

// Round 9
// 352.037 us; speedup vs baseline: 1.1223x; 1.0061x over previous
//
#include <hip/hip_runtime.h>
#include <stdint.h>

#define B_ROWS 2048
#define D2_DIM 256
#define D_DIM 128
#define M_ITEMS 100000
#define M_PAD 100352           // 196 * 512
#define BN_EPS_F 1e-5f
#define COS_EPS_F 1e-6f
#define LEAKY_F 0.01f

#define BNI 128                // items per tile
#define BK 32                  // K per stage
#define SUPER 4                // item tiles per block -> 512 items/block

typedef __bf16 bf16x8 __attribute__((ext_vector_type(8)));
typedef float f32x4 __attribute__((ext_vector_type(4)));

// bf16 hi/lo split planes (device globals; rebuilt every call)
__device__ unsigned short g_Aph[B_ROWS * D_DIM];
__device__ unsigned short g_Apl[B_ROWS * D_DIM];
__device__ unsigned short g_Bph[M_PAD * D_DIM];
__device__ unsigned short g_Bpl[M_PAD * D_DIM];

__device__ __forceinline__ unsigned bf16_rne(float f) {
  unsigned u = __float_as_uint(f);
  return (u + 0x7fffu + ((u >> 16) & 1u)) >> 16;
}
__device__ __forceinline__ void split_bf16(float v, unsigned short& hi, unsigned short& lo) {
  unsigned h = bf16_rne(v);
  float hf = __uint_as_float(h << 16);
  unsigned l = bf16_rne(v - hf);   // exact residual
  hi = (unsigned short)h; lo = (unsigned short)l;
}
__device__ __forceinline__ void gload16(const void* g, void* l) {
  __builtin_amdgcn_global_load_lds(
      (const __attribute__((address_space(1))) void*)g,
      (__attribute__((address_space(3))) void*)l, 16, 0, 0);
}

// ---------- kernel 1: h = item_feature @ W + b ----------
__global__ void k_gemm1(const float* __restrict__ A, const float* __restrict__ W,
                        const float* __restrict__ bias, float* __restrict__ h) {
  __shared__ float arow[D2_DIM];
  const int r = blockIdx.x;
  const int c = threadIdx.x;  // 128
  arow[c] = A[r * D2_DIM + c];
  arow[c + 128] = A[r * D2_DIM + c + 128];
  __syncthreads();
  float acc = 0.f;
#pragma unroll 8
  for (int k = 0; k < D2_DIM; k++) acc = fmaf(arow[k], W[k * D_DIM + c], acc);
  h[r * D_DIM + c] = acc + bias[c];
}

// ---------- kernel 2: per-column mean/var -> scale/shift ----------
__global__ void k_bnstats(const float* __restrict__ h, const float* __restrict__ gamma,
                          const float* __restrict__ beta, float* __restrict__ scale,
                          float* __restrict__ shift) {
  const int c = blockIdx.x;
  const int t = threadIdx.x;  // 256
  double s = 0.0, sq = 0.0;
  for (int r = t; r < B_ROWS; r += 256) {
    double v = (double)h[r * D_DIM + c];
    s += v; sq += v * v;
  }
  __shared__ double ls[256], lq[256];
  ls[t] = s; lq[t] = sq;
  __syncthreads();
  for (int off = 128; off; off >>= 1) {
    if (t < off) { ls[t] += ls[t + off]; lq[t] += lq[t + off]; }
    __syncthreads();
  }
  if (t == 0) {
    double mean = ls[0] / (double)B_ROWS;
    double var = lq[0] / (double)B_ROWS - mean * mean;
    float sc = (float)((double)gamma[c] / sqrt(var + (double)BN_EPS_F));
    scale[c] = sc;
    shift[c] = beta[c] - (float)mean * sc;
  }
}

// ---------- kernel 3: uf = leaky(bn(h)) -> bf16 hi/lo planes ----------
__global__ void k_norm_split(const float* __restrict__ h, const float* __restrict__ scale,
                             const float* __restrict__ shift) {
  int i = blockIdx.x * 256 + threadIdx.x;
  if (i >= B_ROWS * D_DIM) return;
  int c = i & (D_DIM - 1);
  float v = fmaf(h[i], scale[c], shift[c]);
  v = v >= 0.f ? v : LEAKY_F * v;
  unsigned short hi, lo;
  split_bf16(v, hi, lo);
  g_Aph[i] = hi; g_Apl[i] = lo;
}

// ---------- kernel 4: all_items -> bf16 hi/lo planes (pad rows zeroed) ----------
__global__ void k_build_items(const float* __restrict__ items) {
  long long t = (long long)blockIdx.x * 256 + threadIdx.x;
  long long base = t * 4;
  if (base >= (long long)M_PAD * D_DIM) return;
  float4 v;
  if (base < (long long)M_ITEMS * D_DIM) v = *(const float4*)&items[base];
  else v = make_float4(0.f, 0.f, 0.f, 0.f);
  ushort4 hv, lv;
  split_bf16(v.x, hv.x, lv.x);
  split_bf16(v.y, hv.y, lv.y);
  split_bf16(v.z, hv.z, lv.z);
  split_bf16(v.w, hv.w, lv.w);
  *(ushort4*)&g_Bph[base] = hv;
  *(ushort4*)&g_Bpl[base] = lv;
}

// ---------- kernel 5: init argmax keys ----------
__global__ void k_init(unsigned long long* __restrict__ keys) {
  int i = blockIdx.x * blockDim.x + threadIdx.x;
  if (i < B_ROWS) keys[i] = 0ull;
}

// ---------- kernel 6: MFMA scores + fused argmax ----------
// Same structure as R8 (A hi+lo in regs, B 3-deep 16KB ring, counted vmcnt(4),
// 2-ahead prefetch, 0-conflict swizzle). Fix vs R8: pin occupancy tier with
// amdgpu_waves_per_eu(2,2) so the RA uses the 256-VGPR budget instead of
// targeting 128 VGPR and spilling (R8: WRITE_SIZE 278MB of scratch traffic).
__global__
__attribute__((amdgpu_flat_work_group_size(256, 256), amdgpu_waves_per_eu(2, 2)))
void k_scores_mfma(unsigned long long* __restrict__ keys) {
  __shared__ __align__(16) char smem[49152];   // 3 x (hi 8KB + lo 8KB)

  const int tid = threadIdx.x;
  const int l = tid & 63;
  const int w = tid >> 6;      // 0..3
  const int wm = w >> 1;       // row half
  const int wn = w & 1;        // item half
  const int rowbase = blockIdx.x * 128;          // row-block FAST -> B locality
  const int chunk = blockIdx.y * (SUPER * BNI);  // item chunk slow
  const int lrow = l & 15;
  const int lkg = l >> 4;      // 0..3

  // per-thread constant offsets (computed once)
  int tb0, tb1, ldst;
  {
    const int s0 = tid;
    const int s1 = tid + 256;
    tb0 = (s0 >> 2) * 256 + (((s0 & 3) ^ ((s0 >> 3) & 3)) * 16);
    tb1 = (s1 >> 2) * 256 + (((s1 & 3) ^ ((s1 >> 3) & 3)) * 16);
    ldst = tid * 16;           // LDS dest (linear), +4096 for rep 1
  }
  const char* gBh = (const char*)g_Bph;
  const char* gBl = (const char*)g_Bpl;

  // ---- B stage (hi 8KB @ buf, lo 8KB @ buf+8192), source pre-swizzled ----
  auto STAGEB = [&](int itembase, int ks, char* buf) {
    const size_t ub = (size_t)itembase * 256 + (size_t)ks * 2;
    gload16(gBh + ub + tb0, buf + ldst);
    gload16(gBl + ub + tb0, buf + 8192 + ldst);
    gload16(gBh + ub + tb1, buf + ldst + 4096);
    gload16(gBl + ub + tb1, buf + 8192 + ldst + 4096);
  };

  // ---- prologue: stages 0,1 in flight, then A-hi/A-lo -> regs ----
  STAGEB(chunk, 0, smem);
  STAGEB(chunk, BK, smem + 16384);

  bf16x8 ah[4][4], al[4][4];
  const int ar = rowbase + wm * 64 + lrow;
#pragma unroll
  for (int mi = 0; mi < 4; mi++)
#pragma unroll
    for (int kf = 0; kf < 4; kf++) {
      const size_t off = (size_t)(ar + mi * 16) * D_DIM + kf * 32 + lkg * 8;
      ah[mi][kf] = *(const bf16x8*)&g_Aph[off];
      al[mi][kf] = *(const bf16x8*)&g_Apl[off];
    }

  // ds_read base: all 16 reads/step = base + imm(buf*16384 + plane*8192 + ni*1024)
  char* lbase = smem + wn * 4096 + lrow * 64 + ((lkg ^ ((lrow >> 1) & 3)) << 4);

  float bestv[16];
  int besti[16];
#pragma unroll
  for (int q = 0; q < 16; q++) { bestv[q] = -3.0e38f; besti[q] = 0x7fffffff; }

  f32x4 acc[4][4];
#pragma unroll
  for (int mi = 0; mi < 4; mi++)
#pragma unroll
    for (int ni = 0; ni < 4; ni++) acc[mi][ni] = (f32x4)(0.0f);

#pragma unroll
  for (int s = 0; s < SUPER; s++) {
    const int itembase = chunk + s * BNI;
#pragma unroll
    for (int kf = 0; kf < 4; kf++) {
      const int j = s * 4 + kf;
      // own stage-j landed (stage j+1 stays in flight)
      asm volatile("s_waitcnt vmcnt(4)" ::: "memory");
      __builtin_amdgcn_s_barrier();   // all waves' stage-j landed; buf[(j+2)%3] free
      {
        const int q = j + 2;          // prefetch 2 steps ahead (tail: dummy reload)
        const int qt = (q >> 2) & (SUPER - 1);
        STAGEB(chunk + qt * BNI, (q & 3) * BK, smem + (q % 3) * 16384);
      }
      const int jb = (j % 3) * 16384;   // compile-time (loop fully unrolled)
      bf16x8 bh[4], bl[4];
#pragma unroll
      for (int ni = 0; ni < 4; ni++) {
        bh[ni] = *(const bf16x8*)(lbase + jb + ni * 1024);
        bl[ni] = *(const bf16x8*)(lbase + jb + 8192 + ni * 1024);
      }
      __builtin_amdgcn_s_setprio(1);
#pragma unroll
      for (int mi = 0; mi < 4; mi++)
#pragma unroll
        for (int ni = 0; ni < 4; ni++) {
          f32x4 c = acc[mi][ni];
          c = __builtin_amdgcn_mfma_f32_16x16x32_bf16(ah[mi][kf], bh[ni], c, 0, 0, 0);
          c = __builtin_amdgcn_mfma_f32_16x16x32_bf16(al[mi][kf], bh[ni], c, 0, 0, 0);
          c = __builtin_amdgcn_mfma_f32_16x16x32_bf16(ah[mi][kf], bl[ni], c, 0, 0, 0);
          acc[mi][ni] = c;
        }
      __builtin_amdgcn_s_setprio(0);
    }
    // fold item tile into running best; reset acc
#pragma unroll
    for (int mi = 0; mi < 4; mi++)
#pragma unroll
      for (int ni = 0; ni < 4; ni++) {
        const int col = itembase + wn * 64 + ni * 16 + lrow;
        const bool valid = col < M_ITEMS;
#pragma unroll
        for (int reg = 0; reg < 4; reg++) {
          const float v = acc[mi][ni][reg];
          const int q = mi * 4 + reg;
          if (valid && v > bestv[q]) { bestv[q] = v; besti[q] = col; }
        }
        acc[mi][ni] = (f32x4)(0.0f);
      }
  }
  asm volatile("s_waitcnt vmcnt(0)" ::: "memory");  // drain dummy tail prefetches

  // reduce across 16 item-lanes, then one atomicMax per row
#pragma unroll
  for (int q = 0; q < 16; q++) {
    float v = bestv[q];
    int bi = besti[q];
#pragma unroll
    for (int off = 1; off < 16; off <<= 1) {
      float ov = __shfl_xor(v, off, 16);
      int oi = __shfl_xor(bi, off, 16);
      if (ov > v || (ov == v && oi < bi)) { v = ov; bi = oi; }
    }
    if (lrow == 0) {
      const int row = rowbase + wm * 64 + (q >> 2) * 16 + lkg * 4 + (q & 3);
      unsigned u = __float_as_uint(v);
      u = (u & 0x80000000u) ? ~u : (u | 0x80000000u);
      unsigned long long key =
          ((unsigned long long)u << 32) | (unsigned)(~(unsigned)bi);
      atomicMax(&keys[row], key);
    }
  }
}

// ---------- kernel 7: unpack top1, gather, cosine sim ----------
__global__ void k_post(const unsigned long long* __restrict__ keys,
                       const int* __restrict__ uid,
                       const float* __restrict__ items,
                       float* __restrict__ out, float* __restrict__ sims,
                       float* __restrict__ rl) {
  int r = blockIdx.x * blockDim.x + threadIdx.x;
  if (r >= B_ROWS) return;
  unsigned long long key = keys[r];
  int idx = (int)(~(unsigned)(key & 0xFFFFFFFFull));
  out[r] = (float)idx;
  int orig = uid[2 * r + 1];
  const float* a = items + (long long)orig * D_DIM;
  const float* c = items + (long long)idx * D_DIM;
  float aa = 0.f, cc = 0.f, ac = 0.f;
#pragma unroll 4
  for (int d = 0; d < D_DIM; d++) {
    float x = a[d], y = c[d];
    aa = fmaf(x, x, aa);
    cc = fmaf(y, y, cc);
    ac = fmaf(x, y, ac);
  }
  float na = fmaxf(sqrtf(aa), COS_EPS_F);
  float nc = fmaxf(sqrtf(cc), COS_EPS_F);
  float sim = ac / (na * nc);
  sim = (sim + 1.f) * 0.5f;
  sims[r] = sim;
  rl[r] = fmaxf(sim - 0.5f, 0.f);
}

// ---------- kernel 8: deterministic final means ----------
__global__ void k_final(const float* __restrict__ sims, const float* __restrict__ rl,
                        float* __restrict__ out) {
  __shared__ float s1[256], s2[256];
  int t = threadIdx.x;
  float a = 0.f, b = 0.f;
  for (int r = t; r < B_ROWS; r += 256) { a += rl[r]; b += sims[r]; }
  s1[t] = a; s2[t] = b;
  __syncthreads();
  for (int off = 128; off; off >>= 1) {
    if (t < off) { s1[t] += s1[t + off]; s2[t] += s2[t + off]; }
    __syncthreads();
  }
  if (t == 0) {
    out[B_ROWS] = s1[0] / (float)B_ROWS;
    out[B_ROWS + 1] = s2[0] / (float)B_ROWS;
  }
}

extern "C" void kernel_launch(void* const* d_in, const int* in_sizes, int n_in,
                              void* d_out, int out_size, void* d_ws, size_t ws_size,
                              hipStream_t stream) {
  const float* item_feature = (const float*)d_in[0];
  const float* all_items    = (const float*)d_in[1];
  const int*   uid          = (const int*)d_in[2];
  const float* W            = (const float*)d_in[3];
  const float* bias         = (const float*)d_in[4];
  const float* gamma        = (const float*)d_in[5];
  const float* beta         = (const float*)d_in[6];
  float* out = (float*)d_out;

  float* h     = (float*)d_ws;             // 2048*128
  float* scale = h + B_ROWS * D_DIM;       // 128
  float* shift = scale + D_DIM;            // 128
  unsigned long long* keys = (unsigned long long*)(shift + D_DIM);  // 2048
  float* sims  = (float*)(keys + B_ROWS);  // 2048
  float* rl    = sims + B_ROWS;            // 2048

  k_gemm1<<<B_ROWS, D_DIM, 0, stream>>>(item_feature, W, bias, h);
  k_bnstats<<<D_DIM, 256, 0, stream>>>(h, gamma, beta, scale, shift);
  k_norm_split<<<(B_ROWS * D_DIM + 255) / 256, 256, 0, stream>>>(h, scale, shift);
  k_build_items<<<(M_PAD * D_DIM / 4 + 255) / 256, 256, 0, stream>>>(all_items);
  k_init<<<(B_ROWS + 255) / 256, 256, 0, stream>>>(keys);
  dim3 sg(B_ROWS / 128, M_PAD / (SUPER * BNI));   // x = row-block (fast), y = item chunk
  k_scores_mfma<<<sg, 256, 0, stream>>>(keys);
  k_post<<<(B_ROWS + 255) / 256, 256, 0, stream>>>(keys, uid, all_items, out, sims, rl);
  k_final<<<1, 256, 0, stream>>>(sims, rl, out);
}